// Round 2
// baseline (1072.805 us; speedup 1.0000x reference)
//
#include <hip/hip_runtime.h>

// Problem constants (fixed by the reference setup)
#define NN 100000          // N_NODES
#define NE 1600000         // N_EDGES
#define IND 128            // IN_DIM
#define FD 32              // OUT_DIM
#define NH 8               // HEADS
#define HF 256             // NH*FD
#define ETOT 1700000       // NE + NN self loops

// ---------------------------------------------------------------------------
// K1: projection GEMM  h[n][c] = sum_k X[n][k] * W[k][c]
// 16 nodes x 256 cols per block, 256 threads, LDS-staged X tile.
// ---------------------------------------------------------------------------
__global__ __launch_bounds__(256) void k_gemm(const float* __restrict__ X,
                                              const float* __restrict__ W,
                                              float* __restrict__ Hout) {
  __shared__ __align__(16) float Xs[16 * 132];   // +4 pad breaks 128-stride
  const int n0 = blockIdx.x * 16;
  const int t = threadIdx.x;
#pragma unroll
  for (int j = 0; j < 8; ++j) {
    int idx = t + j * 256;          // 0..2047
    int r = idx >> 7, c = idx & 127;
    Xs[r * 132 + c] = X[(n0 + r) * IND + c];
  }
  __syncthreads();

  const int cg = t >> 2;            // 0..63
  const int c0 = cg * 4;
  const int ng = t & 3;

  float4 acc[4];
#pragma unroll
  for (int i = 0; i < 4; ++i) acc[i] = make_float4(0.f, 0.f, 0.f, 0.f);

  for (int k0 = 0; k0 < IND; k0 += 4) {
    const float4 w0 = *(const float4*)(W + (k0 + 0) * HF + c0);
    const float4 w1 = *(const float4*)(W + (k0 + 1) * HF + c0);
    const float4 w2 = *(const float4*)(W + (k0 + 2) * HF + c0);
    const float4 w3 = *(const float4*)(W + (k0 + 3) * HF + c0);
#pragma unroll
    for (int i = 0; i < 4; ++i) {
      const float4 xv = *(const float4*)(Xs + (ng * 4 + i) * 132 + k0);
      acc[i].x += xv.x * w0.x + xv.y * w1.x + xv.z * w2.x + xv.w * w3.x;
      acc[i].y += xv.x * w0.y + xv.y * w1.y + xv.z * w2.y + xv.w * w3.y;
      acc[i].z += xv.x * w0.z + xv.y * w1.z + xv.z * w2.z + xv.w * w3.z;
      acc[i].w += xv.x * w0.w + xv.y * w1.w + xv.z * w2.w + xv.w * w3.w;
    }
  }
#pragma unroll
  for (int i = 0; i < 4; ++i) {
    *(float4*)(Hout + (n0 + ng * 4 + i) * HF + c0) = acc[i];
  }
}

// ---------------------------------------------------------------------------
// K2: per-(node,head) attention logits
// ---------------------------------------------------------------------------
__global__ __launch_bounds__(256) void k_logits(const float* __restrict__ Hh,
                                                const float* __restrict__ att_src,
                                                const float* __restrict__ att_dst,
                                                float* __restrict__ a_s,
                                                float* __restrict__ a_d) {
  int tid = blockIdx.x * 256 + threadIdx.x;
  if (tid >= NN * NH) return;
  int n = tid >> 3, hh = tid & 7;
  const float4* hv = (const float4*)(Hh + n * HF + hh * FD);
  const float4* v1 = (const float4*)(att_src + hh * FD);
  const float4* v2 = (const float4*)(att_dst + hh * FD);
  float s1 = 0.f, s2 = 0.f;
#pragma unroll
  for (int j = 0; j < 8; ++j) {
    float4 h4 = hv[j], a1 = v1[j], a2 = v2[j];
    s1 += h4.x * a1.x + h4.y * a1.y + h4.z * a1.z + h4.w * a1.w;
    s2 += h4.x * a2.x + h4.y * a2.y + h4.z * a2.z + h4.w * a2.w;
  }
  a_s[tid] = s1;
  a_d[tid] = s2;
}

// ---------------------------------------------------------------------------
// K3: softmax denominators (no max pass: logits bounded, fp32 exp is safe;
// alpha/denom is mathematically identical to the reference's shifted form)
// ---------------------------------------------------------------------------
__global__ __launch_bounds__(256) void k_denom(const int* __restrict__ ei,
                                               const float* __restrict__ a_s,
                                               const float* __restrict__ a_d,
                                               float* __restrict__ den) {
  int tid = blockIdx.x * 256 + threadIdx.x;
  if (tid >= ETOT * NH) return;
  int e = tid >> 3, hh = tid & 7;
  int s, d;
  if (e < NE) { s = ei[e]; d = ei[NE + e]; } else { s = d = e - NE; }
  float lg = a_s[s * NH + hh] + a_d[d * NH + hh];
  lg = lg > 0.f ? lg : 0.2f * lg;
  __hip_atomic_fetch_add(&den[d * NH + hh], __expf(lg),
                         __ATOMIC_RELAXED, __HIP_MEMORY_SCOPE_AGENT);
}

// ---------------------------------------------------------------------------
// K4: aggregation, restructured. 8 threads per edge (lane q = head q).
// Each lane computes ITS head's alpha once (1 expf), shares the 8 alphas
// across the edge's lane-group via __shfl(width=8), gathers float4 chunks
// of the src row, and does 4 atomics. Kills the 32x-redundant expf/divide
// of the previous version.
// ---------------------------------------------------------------------------
__global__ __launch_bounds__(256) void k_aggr(const int* __restrict__ ei,
                                              const float* __restrict__ a_s,
                                              const float* __restrict__ a_d,
                                              const float* __restrict__ den,
                                              const float* __restrict__ Hh,
                                              float* __restrict__ oac) {
  int tid = blockIdx.x * 256 + threadIdx.x;
  if (tid >= ETOT * NH) return;      // 13.6M threads, exact multiple of 256
  int e = tid >> 3, q = tid & 7;     // q = this lane's head AND its f4-chunk
  int s, d;
  if (e < NE) { s = ei[e]; d = ei[NE + e]; } else { s = d = e - NE; }

  // my head's alpha (coalesced: 8 lanes of an edge read 8 contiguous floats)
  float lg = a_s[s * NH + q] + a_d[d * NH + q];
  lg = lg > 0.f ? lg : 0.2f * lg;
  float my_alpha = __expf(lg) / (den[d * NH + q] + 1e-16f);

  const float4* hrow = (const float4*)(Hh + s * HF);   // 64 float4 chunks
  float4 acc = make_float4(0.f, 0.f, 0.f, 0.f);
#pragma unroll
  for (int h = 0; h < NH; ++h) {
    float a = __shfl(my_alpha, h, 8);         // head h's alpha from lane h
    float4 hv = hrow[h * 8 + q];              // h[s][h*32 + q*4 .. +3]
    acc.x += a * hv.x;
    acc.y += a * hv.y;
    acc.z += a * hv.z;
    acc.w += a * hv.w;
  }
  float* op = oac + d * FD + q * 4;
  __hip_atomic_fetch_add(op + 0, acc.x, __ATOMIC_RELAXED, __HIP_MEMORY_SCOPE_AGENT);
  __hip_atomic_fetch_add(op + 1, acc.y, __ATOMIC_RELAXED, __HIP_MEMORY_SCOPE_AGENT);
  __hip_atomic_fetch_add(op + 2, acc.z, __ATOMIC_RELAXED, __HIP_MEMORY_SCOPE_AGENT);
  __hip_atomic_fetch_add(op + 3, acc.w, __ATOMIC_RELAXED, __HIP_MEMORY_SCOPE_AGENT);
}

// ---------------------------------------------------------------------------
// K5: mean over heads + bias
// ---------------------------------------------------------------------------
__global__ __launch_bounds__(256) void k_final(const float* __restrict__ oac,
                                               const float* __restrict__ bias,
                                               float* __restrict__ out) {
  int tid = blockIdx.x * 256 + threadIdx.x;
  if (tid >= NN * FD) return;
  out[tid] = oac[tid] * 0.125f + bias[tid & 31];
}

// ---------------------------------------------------------------------------
// Workspace layout (floats):
//   Hh   [0,          25,600,000)   102.4 MB
//   a_s  [25,600,000, 26,400,000)     3.2 MB
//   a_d  [26,400,000, 27,200,000)     3.2 MB
//   den  [27,200,000, 28,000,000)     3.2 MB
//   oac  [28,000,000, 31,200,000)    12.8 MB
// ---------------------------------------------------------------------------
extern "C" void kernel_launch(void* const* d_in, const int* in_sizes, int n_in,
                              void* d_out, int out_size, void* d_ws, size_t ws_size,
                              hipStream_t stream) {
  const float* X       = (const float*)d_in[0];
  const int*   ei      = (const int*)d_in[1];
  const float* W       = (const float*)d_in[2];
  const float* att_src = (const float*)d_in[3];
  const float* att_dst = (const float*)d_in[4];
  const float* bias    = (const float*)d_in[5];
  float* out = (float*)d_out;
  float* ws  = (float*)d_ws;

  float* Hh  = ws;
  float* a_s = ws + 25600000;
  float* a_d = ws + 26400000;
  float* den = ws + 27200000;
  float* oac = ws + 28000000;

  // zero den + oac (contiguous 4M floats); ws is re-poisoned before each call
  hipMemsetAsync(den, 0, (size_t)4000000 * sizeof(float), stream);

  k_gemm  <<<NN / 16, 256, 0, stream>>>(X, W, Hh);
  k_logits<<<(NN * NH + 255) / 256, 256, 0, stream>>>(Hh, att_src, att_dst, a_s, a_d);
  k_denom <<<(ETOT * NH + 255) / 256, 256, 0, stream>>>(ei, a_s, a_d, den);
  k_aggr  <<<(ETOT * NH) / 256, 256, 0, stream>>>(ei, a_s, a_d, den, Hh, oac);
  k_final <<<(NN * FD + 255) / 256, 256, 0, stream>>>(oac, bias, out);
}

// Round 3
// 677.411 us; speedup vs baseline: 1.5837x; 1.5837x over previous
//
#include <hip/hip_runtime.h>

// Problem constants (fixed by the reference setup)
#define NN 100000          // N_NODES
#define NE 1600000         // N_EDGES
#define IND 128            // IN_DIM
#define FD 32              // OUT_DIM
#define NH 8               // HEADS
#define HF 256             // NH*FD
#define ETOT 1700000       // NE + NN self loops

// ---------------------------------------------------------------------------
// K1: projection GEMM  h[n][c] = sum_k X[n][k] * W[k][c]
// 16 nodes x 256 cols per block, 256 threads, LDS-staged X tile.
// ---------------------------------------------------------------------------
__global__ __launch_bounds__(256) void k_gemm(const float* __restrict__ X,
                                              const float* __restrict__ W,
                                              float* __restrict__ Hout) {
  __shared__ __align__(16) float Xs[16 * 132];   // +4 pad breaks 128-stride
  const int n0 = blockIdx.x * 16;
  const int t = threadIdx.x;
#pragma unroll
  for (int j = 0; j < 8; ++j) {
    int idx = t + j * 256;          // 0..2047
    int r = idx >> 7, c = idx & 127;
    Xs[r * 132 + c] = X[(n0 + r) * IND + c];
  }
  __syncthreads();

  const int cg = t >> 2;            // 0..63
  const int c0 = cg * 4;
  const int ng = t & 3;

  float4 acc[4];
#pragma unroll
  for (int i = 0; i < 4; ++i) acc[i] = make_float4(0.f, 0.f, 0.f, 0.f);

  for (int k0 = 0; k0 < IND; k0 += 4) {
    const float4 w0 = *(const float4*)(W + (k0 + 0) * HF + c0);
    const float4 w1 = *(const float4*)(W + (k0 + 1) * HF + c0);
    const float4 w2 = *(const float4*)(W + (k0 + 2) * HF + c0);
    const float4 w3 = *(const float4*)(W + (k0 + 3) * HF + c0);
#pragma unroll
    for (int i = 0; i < 4; ++i) {
      const float4 xv = *(const float4*)(Xs + (ng * 4 + i) * 132 + k0);
      acc[i].x += xv.x * w0.x + xv.y * w1.x + xv.z * w2.x + xv.w * w3.x;
      acc[i].y += xv.x * w0.y + xv.y * w1.y + xv.z * w2.y + xv.w * w3.y;
      acc[i].z += xv.x * w0.z + xv.y * w1.z + xv.z * w2.z + xv.w * w3.z;
      acc[i].w += xv.x * w0.w + xv.y * w1.w + xv.z * w2.w + xv.w * w3.w;
    }
  }
#pragma unroll
  for (int i = 0; i < 4; ++i) {
    *(float4*)(Hout + (n0 + ng * 4 + i) * HF + c0) = acc[i];
  }
}

// ---------------------------------------------------------------------------
// K2: per-(node,head) attention logits
// ---------------------------------------------------------------------------
__global__ __launch_bounds__(256) void k_logits(const float* __restrict__ Hh,
                                                const float* __restrict__ att_src,
                                                const float* __restrict__ att_dst,
                                                float* __restrict__ a_s,
                                                float* __restrict__ a_d) {
  int tid = blockIdx.x * 256 + threadIdx.x;
  if (tid >= NN * NH) return;
  int n = tid >> 3, hh = tid & 7;
  const float4* hv = (const float4*)(Hh + n * HF + hh * FD);
  const float4* v1 = (const float4*)(att_src + hh * FD);
  const float4* v2 = (const float4*)(att_dst + hh * FD);
  float s1 = 0.f, s2 = 0.f;
#pragma unroll
  for (int j = 0; j < 8; ++j) {
    float4 h4 = hv[j], a1 = v1[j], a2 = v2[j];
    s1 += h4.x * a1.x + h4.y * a1.y + h4.z * a1.z + h4.w * a1.w;
    s2 += h4.x * a2.x + h4.y * a2.y + h4.z * a2.z + h4.w * a2.w;
  }
  a_s[tid] = s1;
  a_d[tid] = s2;
}

// ---------------------------------------------------------------------------
// K3: softmax denominators (no max pass: logits bounded, fp32 exp is safe;
// alpha/denom is mathematically identical to the reference's shifted form)
// ---------------------------------------------------------------------------
__global__ __launch_bounds__(256) void k_denom(const int* __restrict__ ei,
                                               const float* __restrict__ a_s,
                                               const float* __restrict__ a_d,
                                               float* __restrict__ den) {
  int tid = blockIdx.x * 256 + threadIdx.x;
  if (tid >= ETOT * NH) return;
  int e = tid >> 3, hh = tid & 7;
  int s, d;
  if (e < NE) { s = ei[e]; d = ei[NE + e]; } else { s = d = e - NE; }
  float lg = a_s[s * NH + hh] + a_d[d * NH + hh];
  lg = lg > 0.f ? lg : 0.2f * lg;
  __hip_atomic_fetch_add(&den[d * NH + hh], __expf(lg),
                         __ATOMIC_RELAXED, __HIP_MEMORY_SCOPE_AGENT);
}

// ---------------------------------------------------------------------------
// K4: aggregation. 32 lanes per edge (lane f = output feature f), ONE atomic
// per lane to consecutive addresses -> coalesces to a single 128-B atomic
// line op per edge (WRITE_SIZE lesson from round 2). Alpha computed once per
// 8 lanes (lane f handles head q=f&7: 1 expf + 1 div per thread, 8x less
// transcendental work than round 1) and broadcast via __shfl width-32.
// ---------------------------------------------------------------------------
__global__ __launch_bounds__(256) void k_aggr(const int* __restrict__ ei,
                                              const float* __restrict__ a_s,
                                              const float* __restrict__ a_d,
                                              const float* __restrict__ den,
                                              const float* __restrict__ Hh,
                                              float* __restrict__ oac) {
  int tid = blockIdx.x * 256 + threadIdx.x;
  if (tid >= ETOT * FD) return;      // 54.4M threads, exact multiple of 256
  int e = tid >> 5, f = tid & 31;
  int s, d;
  if (e < NE) { s = ei[e]; d = ei[NE + e]; } else { s = d = e - NE; }

  // lane f computes head (f&7)'s alpha; 4x redundancy across the 32 lanes
  int q = f & 7;
  float lg = a_s[s * NH + q] + a_d[d * NH + q];
  lg = lg > 0.f ? lg : 0.2f * lg;
  float my_alpha = __expf(lg) / (den[d * NH + q] + 1e-16f);

  const float* hs = Hh + s * HF + f;
  float msg = 0.f;
#pragma unroll
  for (int h = 0; h < NH; ++h) {
    float a = __shfl(my_alpha, h, 32);   // head h's alpha from lane h of this edge's segment
    msg += a * hs[h * FD];               // 32 lanes read 128 contiguous bytes
  }
  __hip_atomic_fetch_add(&oac[d * FD + f], msg,
                         __ATOMIC_RELAXED, __HIP_MEMORY_SCOPE_AGENT);
}

// ---------------------------------------------------------------------------
// K5: mean over heads + bias
// ---------------------------------------------------------------------------
__global__ __launch_bounds__(256) void k_final(const float* __restrict__ oac,
                                               const float* __restrict__ bias,
                                               float* __restrict__ out) {
  int tid = blockIdx.x * 256 + threadIdx.x;
  if (tid >= NN * FD) return;
  out[tid] = oac[tid] * 0.125f + bias[tid & 31];
}

// ---------------------------------------------------------------------------
// Workspace layout (floats):
//   Hh   [0,          25,600,000)   102.4 MB
//   a_s  [25,600,000, 26,400,000)     3.2 MB
//   a_d  [26,400,000, 27,200,000)     3.2 MB
//   den  [27,200,000, 28,000,000)     3.2 MB
//   oac  [28,000,000, 31,200,000)    12.8 MB
// ---------------------------------------------------------------------------
extern "C" void kernel_launch(void* const* d_in, const int* in_sizes, int n_in,
                              void* d_out, int out_size, void* d_ws, size_t ws_size,
                              hipStream_t stream) {
  const float* X       = (const float*)d_in[0];
  const int*   ei      = (const int*)d_in[1];
  const float* W       = (const float*)d_in[2];
  const float* att_src = (const float*)d_in[3];
  const float* att_dst = (const float*)d_in[4];
  const float* bias    = (const float*)d_in[5];
  float* out = (float*)d_out;
  float* ws  = (float*)d_ws;

  float* Hh  = ws;
  float* a_s = ws + 25600000;
  float* a_d = ws + 26400000;
  float* den = ws + 27200000;
  float* oac = ws + 28000000;

  // zero den + oac (contiguous 4M floats); ws is re-poisoned before each call
  hipMemsetAsync(den, 0, (size_t)4000000 * sizeof(float), stream);

  k_gemm  <<<NN / 16, 256, 0, stream>>>(X, W, Hh);
  k_logits<<<(NN * NH + 255) / 256, 256, 0, stream>>>(Hh, att_src, att_dst, a_s, a_d);
  k_denom <<<(ETOT * NH + 255) / 256, 256, 0, stream>>>(ei, a_s, a_d, den);
  k_aggr  <<<(ETOT * FD) / 256, 256, 0, stream>>>(ei, a_s, a_d, den, Hh, oac);
  k_final <<<(NN * FD + 255) / 256, 256, 0, stream>>>(oac, bias, out);
}

// Round 4
// 506.635 us; speedup vs baseline: 2.1175x; 1.3371x over previous
//
#include <hip/hip_runtime.h>

// Problem constants (fixed by the reference setup)
#define NN 100000          // N_NODES
#define NE 1600000         // N_EDGES
#define IND 128            // IN_DIM
#define FD 32              // OUT_DIM
#define NH 8               // HEADS
#define HF 256             // NH*FD
#define ETOT 1700000       // NE + NN self loops

// bf16 helpers (RNE), bit-level to avoid header variance
static __device__ __forceinline__ unsigned short f2bf(float f) {
  union { float f; unsigned u; } v; v.f = f;
  unsigned r = v.u + 0x7FFF + ((v.u >> 16) & 1);
  return (unsigned short)(r >> 16);
}
static __device__ __forceinline__ float bf2f(unsigned short u) {
  union { unsigned u; float f; } v; v.u = ((unsigned)u) << 16;
  return v.f;
}

// ---------------------------------------------------------------------------
// K1: projection GEMM fused with attention logits.
// 16 nodes x 256 cols per block (a block owns COMPLETE h rows).
//  - h stored as bf16 (halves the k_aggr gather bytes; round-3 post-mortem
//    showed k_aggr is gather-byte-bound, not VALU-bound)
//  - a_src / a_dst computed in fp32 from the fp32 accumulators (exact),
//    via padded-LDS cross-thread reduction
//  - den slots of the packed ADD record zeroed here (no separate memset)
// ---------------------------------------------------------------------------
__global__ __launch_bounds__(256) void k_gemm(const float* __restrict__ X,
                                              const float* __restrict__ W,
                                              const float* __restrict__ att_src,
                                              const float* __restrict__ att_dst,
                                              unsigned short* __restrict__ HhB,
                                              float* __restrict__ AS,
                                              float* __restrict__ ADD) {
  __shared__ __align__(16) float Xs[16 * 132];   // +4 pad breaks 128-stride
  __shared__ float redS[16 * 65];                // 65 stride: bank-conflict-free
  __shared__ float redD[16 * 65];
  const int n0 = blockIdx.x * 16;
  const int t = threadIdx.x;
#pragma unroll
  for (int j = 0; j < 8; ++j) {
    int idx = t + j * 256;          // 0..2047
    int r = idx >> 7, c = idx & 127;
    Xs[r * 132 + c] = X[(n0 + r) * IND + c];
  }
  __syncthreads();

  const int cg = t >> 2;            // 0..63  (column group)
  const int c0 = cg * 4;            // cols c0..c0+3, all inside head c0>>5
  const int ng = t & 3;             // node group (rows ng*4..ng*4+3)

  float4 acc[4];
#pragma unroll
  for (int i = 0; i < 4; ++i) acc[i] = make_float4(0.f, 0.f, 0.f, 0.f);

  for (int k0 = 0; k0 < IND; k0 += 4) {
    const float4 w0 = *(const float4*)(W + (k0 + 0) * HF + c0);
    const float4 w1 = *(const float4*)(W + (k0 + 1) * HF + c0);
    const float4 w2 = *(const float4*)(W + (k0 + 2) * HF + c0);
    const float4 w3 = *(const float4*)(W + (k0 + 3) * HF + c0);
#pragma unroll
    for (int i = 0; i < 4; ++i) {
      const float4 xv = *(const float4*)(Xs + (ng * 4 + i) * 132 + k0);
      acc[i].x += xv.x * w0.x + xv.y * w1.x + xv.z * w2.x + xv.w * w3.x;
      acc[i].y += xv.x * w0.y + xv.y * w1.y + xv.z * w2.y + xv.w * w3.y;
      acc[i].z += xv.x * w0.z + xv.y * w1.z + xv.z * w2.z + xv.w * w3.z;
      acc[i].w += xv.x * w0.w + xv.y * w1.w + xv.z * w2.w + xv.w * w3.w;
    }
  }

  // epilogue 1: bf16 store of h (8B per row-chunk, aligned)
#pragma unroll
  for (int i = 0; i < 4; ++i) {
    ushort4 u;
    u.x = f2bf(acc[i].x); u.y = f2bf(acc[i].y);
    u.z = f2bf(acc[i].z); u.w = f2bf(acc[i].w);
    *(ushort4*)(HhB + (n0 + ng * 4 + i) * HF + c0) = u;
  }

  // epilogue 2: logits partials (fp32, exact)
  const float4 vs = *(const float4*)(att_src + c0);  // att_src flat [256]
  const float4 vd = *(const float4*)(att_dst + c0);
#pragma unroll
  for (int i = 0; i < 4; ++i) {
    int r = ng * 4 + i;
    redS[r * 65 + cg] = acc[i].x * vs.x + acc[i].y * vs.y +
                        acc[i].z * vs.z + acc[i].w * vs.w;
    redD[r * 65 + cg] = acc[i].x * vd.x + acc[i].y * vd.y +
                        acc[i].z * vd.z + acc[i].w * vd.w;
  }
  __syncthreads();

  // epilogue 3: reduce 8 column-groups per (row, head); 128+128 threads
  if (t < 128) {
    int r = t >> 3, hh = t & 7;
    float s = 0.f;
#pragma unroll
    for (int k = 0; k < 8; ++k) s += redS[r * 65 + hh * 8 + k];
    AS[(n0 + r) * NH + hh] = s;
  } else {
    int tt = t - 128;
    int r = tt >> 3, hh = tt & 7;
    float s = 0.f;
#pragma unroll
    for (int k = 0; k < 8; ++k) s += redD[r * 65 + hh * 8 + k];
    ADD[(n0 + r) * 16 + hh] = s;        // a_dst in slots [0,8)
    ADD[(n0 + r) * 16 + 8 + hh] = 0.f;  // den zeroed in slots [8,16)
  }
}

// ---------------------------------------------------------------------------
// K2: softmax denominators. Packed ADD record -> one cache line per dst.
// (no max pass: logits bounded, fp32 exp is safe; alpha/denom identical to
// the reference's shifted form)
// ---------------------------------------------------------------------------
__global__ __launch_bounds__(256) void k_denom(const int* __restrict__ ei,
                                               const float* __restrict__ AS,
                                               float* __restrict__ ADD) {
  int tid = blockIdx.x * 256 + threadIdx.x;
  if (tid >= ETOT * NH) return;
  int e = tid >> 3, q = tid & 7;
  int s, d;
  if (e < NE) { s = ei[e]; d = ei[NE + e]; } else { s = d = e - NE; }
  float lg = AS[s * NH + q] + ADD[d * 16 + q];
  lg = lg > 0.f ? lg : 0.2f * lg;
  __hip_atomic_fetch_add(&ADD[d * 16 + 8 + q], __expf(lg),
                         __ATOMIC_RELAXED, __HIP_MEMORY_SCOPE_AGENT);
}

// ---------------------------------------------------------------------------
// K3: aggregation. 32 lanes per edge, ONE coalesced atomic per lane
// (single 128-B atomic line op per edge — round-2 lesson). bf16 gather
// (round-3 lesson: gather-byte-bound). Alpha computed once per 8 lanes,
// broadcast via __shfl width-32. dst-side data = one packed line.
// ---------------------------------------------------------------------------
__global__ __launch_bounds__(256) void k_aggr(const int* __restrict__ ei,
                                              const float* __restrict__ AS,
                                              const float* __restrict__ ADD,
                                              const unsigned short* __restrict__ HhB,
                                              float* __restrict__ oac) {
  int tid = blockIdx.x * 256 + threadIdx.x;
  if (tid >= ETOT * FD) return;      // 54.4M threads, exact multiple of 256
  int e = tid >> 5, f = tid & 31;
  int s, d;
  if (e < NE) { s = ei[e]; d = ei[NE + e]; } else { s = d = e - NE; }

  int q = f & 7;                     // this lane's head (4x lane redundancy)
  float lg = AS[s * NH + q] + ADD[d * 16 + q];
  lg = lg > 0.f ? lg : 0.2f * lg;
  float my_alpha = __expf(lg) / (ADD[d * 16 + 8 + q] + 1e-16f);

  const unsigned short* hs = HhB + s * HF + f;
  float msg = 0.f;
#pragma unroll
  for (int h = 0; h < NH; ++h) {
    float a = __shfl(my_alpha, h, 32);   // head h's alpha from lane h
    msg += a * bf2f(hs[h * FD]);         // 32 lanes: 64B contiguous
  }
  __hip_atomic_fetch_add(&oac[d * FD + f], msg,
                         __ATOMIC_RELAXED, __HIP_MEMORY_SCOPE_AGENT);
}

// ---------------------------------------------------------------------------
// K4: mean over heads + bias
// ---------------------------------------------------------------------------
__global__ __launch_bounds__(256) void k_final(const float* __restrict__ oac,
                                               const float* __restrict__ bias,
                                               float* __restrict__ out) {
  int tid = blockIdx.x * 256 + threadIdx.x;
  if (tid >= NN * FD) return;
  out[tid] = oac[tid] * 0.125f + bias[tid & 31];
}

// ---------------------------------------------------------------------------
// Workspace layout (float units):
//   HhB  [0,          12,800,000)  bf16 h, 51.2 MB (25.6M ushorts)
//   AS   [12,800,000, 13,600,000)  a_src [N][8],  3.2 MB
//   ADD  [13,600,000, 15,200,000)  packed a_dst+den [N][16], 6.4 MB (64B rec)
//   oac  [15,200,000, 18,400,000)  accumulator [N][32], 12.8 MB
// ---------------------------------------------------------------------------
extern "C" void kernel_launch(void* const* d_in, const int* in_sizes, int n_in,
                              void* d_out, int out_size, void* d_ws, size_t ws_size,
                              hipStream_t stream) {
  const float* X       = (const float*)d_in[0];
  const int*   ei      = (const int*)d_in[1];
  const float* W       = (const float*)d_in[2];
  const float* att_src = (const float*)d_in[3];
  const float* att_dst = (const float*)d_in[4];
  const float* bias    = (const float*)d_in[5];
  float* out = (float*)d_out;
  float* ws  = (float*)d_ws;

  unsigned short* HhB = (unsigned short*)ws;
  float* AS  = ws + 12800000;
  float* ADD = ws + 13600000;
  float* oac = ws + 15200000;

  // only oac needs zeroing now (den slots zeroed inside k_gemm epilogue)
  hipMemsetAsync(oac, 0, (size_t)3200000 * sizeof(float), stream);

  k_gemm  <<<NN / 16, 256, 0, stream>>>(X, W, att_src, att_dst, HhB, AS, ADD);
  k_denom <<<(ETOT * NH) / 256, 256, 0, stream>>>(ei, AS, ADD);
  k_aggr  <<<(ETOT * FD) / 256, 256, 0, stream>>>(ei, AS, ADD, HhB, oac);
  k_final <<<(NN * FD) / 256, 256, 0, stream>>>(oac, bias, out);
}